// Round 5
// baseline (374.715 us; speedup 1.0000x reference)
//
#include <hip/hip_runtime.h>
#include <hip/hip_bf16.h>

typedef unsigned short u16;
typedef __bf16 bf16x8 __attribute__((ext_vector_type(8)));
typedef float f32x4 __attribute__((ext_vector_type(4)));

#define S_LEN 2048
#define NH 16
#define NB 2
#define HEAD_ELEMS (NB * NH * S_LEN * 64)

#if __has_builtin(__builtin_amdgcn_exp2f)
#define EXP2(x) __builtin_amdgcn_exp2f(x)
#else
#define EXP2(x) exp2f(x)
#endif

// 1/sqrt(64) * log2(e), folded into Wq. Scores come out in log2 units.
#define QSCALE 0.180336880f
#define SHIFT2 30.0f

__device__ __forceinline__ bf16x8 pack8(float4 a, float4 b, float sc) {
    union { bf16x8 v; __hip_bfloat162 h[4]; } r;
    r.h[0] = __float22bfloat162_rn(make_float2(a.x * sc, a.y * sc));
    r.h[1] = __float22bfloat162_rn(make_float2(a.z * sc, a.w * sc));
    r.h[2] = __float22bfloat162_rn(make_float2(b.x * sc, b.y * sc));
    r.h[3] = __float22bfloat162_rn(make_float2(b.z * sc, b.w * sc));
    return r.v;
}

// ---------------- K/Q projection, coalesced epilogue ----------------
// grid (stile 0..255, p 0..1, hhalf 0..1); 4 waves; wave = 16 rows x 2 heads.
// Y = X W^T via A=x-rows, B=W-rows. Block stages [8h][16s][64e] -> 128B-run stores.
__global__ __launch_bounds__(256) void proj_kq(
    const float* __restrict__ kin, const float* __restrict__ qin,
    const float* __restrict__ Wk, const float* __restrict__ Wq,
    u16* __restrict__ Kh, u16* __restrict__ Qh)
{
    __shared__ __align__(16) u16 Yld[8 * 16 * 72];

    const int tid = threadIdx.x;
    const int wave = tid >> 6;
    const int lane = tid & 63;
    const int quad = lane >> 4;
    const int l15 = lane & 15;
    const int stile = blockIdx.x;
    const int p = blockIdx.y;
    const int hh = blockIdx.z;
    const long row0 = (long)stile * 16;
    const int b = (int)(row0 >> 11);
    const int s0 = (int)(row0 & 2047);

    const float* X = p ? qin : kin;
    const float* W = p ? Wq : Wk;
    const float sc = p ? QSCALE : 1.0f;

    // W fragments (B-operand): lane holds W[nt*16+l15][c*32+quad*8 ..+7]
    bf16x8 wf[4][2];
    #pragma unroll
    for (int nt = 0; nt < 4; ++nt) {
        const float* wr = W + (nt * 16 + l15) * 64 + quad * 8;
        wf[nt][0] = pack8(*(const float4*)(wr),      *(const float4*)(wr + 4),  sc);
        wf[nt][1] = pack8(*(const float4*)(wr + 32), *(const float4*)(wr + 36), sc);
    }

    #pragma unroll
    for (int hp = 0; hp < 2; ++hp) {
        const int hl = wave * 2 + hp;            // 0..7
        const int h = hh * 8 + hl;
        const float* xr = X + (row0 + l15) * 1024 + h * 64 + quad * 8;
        bf16x8 a0 = pack8(*(const float4*)(xr),      *(const float4*)(xr + 4),  1.0f);
        bf16x8 a1 = pack8(*(const float4*)(xr + 32), *(const float4*)(xr + 36), 1.0f);
        #pragma unroll
        for (int nt = 0; nt < 4; ++nt) {
            f32x4 c = (f32x4){0.f, 0.f, 0.f, 0.f};
            c = __builtin_amdgcn_mfma_f32_16x16x32_bf16(a0, wf[nt][0], c, 0, 0, 0);
            c = __builtin_amdgcn_mfma_f32_16x16x32_bf16(a1, wf[nt][1], c, 0, 0, 0);
            union { __hip_bfloat162 h2; u16 u[2]; } x01, x23;
            x01.h2 = __float22bfloat162_rn(make_float2(c[0], c[1]));
            x23.h2 = __float22bfloat162_rn(make_float2(c[2], c[3]));
            int base = (hl * 16 + quad * 4) * 72 + nt * 16 + l15;
            Yld[base]       = x01.u[0];
            Yld[base + 72]  = x01.u[1];
            Yld[base + 144] = x23.u[0];
            Yld[base + 216] = x23.u[1];
        }
    }
    __syncthreads();

    u16* dst = p ? Qh : Kh;
    #pragma unroll
    for (int it = 0; it < 4; ++it) {
        int idx = tid + it * 256;                // 0..1023
        int eg = idx & 7, s = (idx >> 3) & 15, hl = idx >> 7;
        int bh = b * NH + hh * 8 + hl;
        *(float4*)(dst + ((long)bh * S_LEN + s0 + s) * 64 + eg * 8) =
            *(const float4*)&Yld[(hl * 16 + s) * 72 + eg * 8];
    }
}

// ---------------- V projection (transposed out), coalesced epilogue ----------------
// grid (stile64 0..63, h 0..15); 4 waves; wave = one 16-s quadrant of V^T 64x64 tile.
// V^T = W X^T via A=W-rows, B=x-rows. LDS tile [64e][72s-stride] -> 128B-run stores.
__global__ __launch_bounds__(256) void proj_v(
    const float* __restrict__ vin, const float* __restrict__ Wv, u16* __restrict__ Vt)
{
    __shared__ __align__(16) u16 Vtile[64 * 72];

    const int tid = threadIdx.x;
    const int wave = tid >> 6;
    const int lane = tid & 63;
    const int quad = lane >> 4;
    const int l15 = lane & 15;
    const long row0 = (long)blockIdx.x * 64;
    const int b = (int)(row0 >> 11);
    const int s0 = (int)(row0 & 2047);
    const int h = blockIdx.y;
    const int bh = b * NH + h;

    bf16x8 wf[4][2];
    #pragma unroll
    for (int dt = 0; dt < 4; ++dt) {
        const float* wr = Wv + (dt * 16 + l15) * 64 + quad * 8;
        wf[dt][0] = pack8(*(const float4*)(wr),      *(const float4*)(wr + 4),  1.0f);
        wf[dt][1] = pack8(*(const float4*)(wr + 32), *(const float4*)(wr + 36), 1.0f);
    }

    const float* xr = vin + (row0 + wave * 16 + l15) * 1024 + h * 64 + quad * 8;
    bf16x8 x0 = pack8(*(const float4*)(xr),      *(const float4*)(xr + 4),  1.0f);
    bf16x8 x1 = pack8(*(const float4*)(xr + 32), *(const float4*)(xr + 36), 1.0f);

    #pragma unroll
    for (int dt = 0; dt < 4; ++dt) {
        f32x4 c = (f32x4){0.f, 0.f, 0.f, 0.f};
        c = __builtin_amdgcn_mfma_f32_16x16x32_bf16(wf[dt][0], x0, c, 0, 0, 0);
        c = __builtin_amdgcn_mfma_f32_16x16x32_bf16(wf[dt][1], x1, c, 0, 0, 0);
        // D[e = dt*16+quad*4+r][s = wave*16+l15]
        int base = (dt * 16 + quad * 4) * 72 + wave * 16 + l15;
        union { __hip_bfloat162 h2; u16 u[2]; } x01, x23;
        x01.h2 = __float22bfloat162_rn(make_float2(c[0], c[1]));
        x23.h2 = __float22bfloat162_rn(make_float2(c[2], c[3]));
        Vtile[base]       = x01.u[0];
        Vtile[base + 72]  = x01.u[1];
        Vtile[base + 144] = x23.u[0];
        Vtile[base + 216] = x23.u[1];
    }
    __syncthreads();

    u16* dst = Vt + (long)bh * 64 * S_LEN + s0;
    #pragma unroll
    for (int it = 0; it < 2; ++it) {
        int idx = tid + it * 256;                // 0..511
        int sg = idx & 7, e = idx >> 3;
        *(float4*)(dst + (long)e * S_LEN + sg * 8) = *(const float4*)&Vtile[e * 72 + sg * 8];
    }
}

// ---------------- attention: wave-autonomous kv-split, K reg-prefetch ----------------
__global__ __launch_bounds__(256, 3) void attn_kernel(
    const u16* __restrict__ Qh, const u16* __restrict__ Kh,
    const u16* __restrict__ Vt, float* __restrict__ out)
{
    __shared__ __align__(16) u16 Pld[4][16 * 72];
    __shared__ __align__(16) float Old[4][64 * 20];
    __shared__ float lbc[4][64];

    const int tid = threadIdx.x;
    const int wave = tid >> 6;
    const int lane = tid & 63;
    const int quad = lane >> 4;
    const int l15 = lane & 15;
    const int qb = blockIdx.x;
    const int bh = blockIdx.y;
    const int b = bh >> 4, h = bh & 15;
    const int q0 = qb * 64;
    const u16* kb = Kh + (long)bh * S_LEN * 64;
    const u16* vb = Vt + (long)bh * 64 * S_LEN;

    // Q fragments (B-operand for S^T = K Q^T)
    bf16x8 qf[4][2];
    {
        const u16* qp = Qh + (long)bh * S_LEN * 64;
        #pragma unroll
        for (int g = 0; g < 4; ++g) {
            const u16* qr = qp + (long)(q0 + g * 16 + l15) * 64 + quad * 8;
            qf[g][0] = *(const bf16x8*)(qr);
            qf[g][1] = *(const bf16x8*)(qr + 32);
        }
    }

    const int rot = 16 * (l15 & 3);
    u16* pbase = &Pld[wave][l15 * 72];
    const int pwc[4] = {( 0 + quad * 4 + rot) & 63, (16 + quad * 4 + rot) & 63,
                        (32 + quad * 4 + rot) & 63, (48 + quad * 4 + rot) & 63};
    const int prc[2] = {(quad * 8 + rot) & 63, (32 + quad * 8 + rot) & 63};

    f32x4 oacc[4][4];
    #pragma unroll
    for (int g = 0; g < 4; ++g)
        #pragma unroll
        for (int dt = 0; dt < 4; ++dt) oacc[g][dt] = (f32x4){0.f, 0.f, 0.f, 0.f};
    float rs[4] = {0.f, 0.f, 0.f, 0.f};

    // K fragments for first tile
    bf16x8 kf[4][2], knx[4][2];
    {
        const u16* kt_p = kb + (long)wave * 64 * 64;
        #pragma unroll
        for (int n = 0; n < 4; ++n) {
            const u16* kr = kt_p + (n * 16 + l15) * 64 + quad * 8;
            kf[n][0] = *(const bf16x8*)(kr);
            kf[n][1] = *(const bf16x8*)(kr + 32);
        }
    }

    for (int kt = wave; kt < S_LEN / 64; kt += 4) {
        // V fragments for current tile (first use ~250 cyc later)
        bf16x8 vf[4][2];
        const u16* vt_p = vb + kt * 64;
        #pragma unroll
        for (int dt = 0; dt < 4; ++dt) {
            const u16* vr = vt_p + (long)(dt * 16 + l15) * S_LEN + quad * 8;
            vf[dt][0] = *(const bf16x8*)(vr);
            vf[dt][1] = *(const bf16x8*)(vr + 32);
        }
        // prefetch next K tile into regs
        if (kt + 4 < S_LEN / 64) {
            const u16* kp = kb + (long)(kt + 4) * 64 * 64;
            #pragma unroll
            for (int n = 0; n < 4; ++n) {
                const u16* kr = kp + (n * 16 + l15) * 64 + quad * 8;
                knx[n][0] = *(const bf16x8*)(kr);
                knx[n][1] = *(const bf16x8*)(kr + 32);
            }
        }

        #pragma unroll
        for (int g = 0; g < 4; ++g) {
            f32x4 sacc[4];
            #pragma unroll
            for (int n = 0; n < 4; ++n) {
                f32x4 c = (f32x4){0.f, 0.f, 0.f, 0.f};
                c = __builtin_amdgcn_mfma_f32_16x16x32_bf16(kf[n][0], qf[g][0], c, 0, 0, 0);
                c = __builtin_amdgcn_mfma_f32_16x16x32_bf16(kf[n][1], qf[g][1], c, 0, 0, 0);
                sacc[n] = c;
            }
            #pragma unroll
            for (int n = 0; n < 4; ++n) {
                float p0 = EXP2(sacc[n][0] - SHIFT2);
                float p1 = EXP2(sacc[n][1] - SHIFT2);
                float p2 = EXP2(sacc[n][2] - SHIFT2);
                float p3 = EXP2(sacc[n][3] - SHIFT2);
                rs[g] += (p0 + p1) + (p2 + p3);
                union { uint2 w; __hip_bfloat162 h2[2]; } pk;
                pk.h2[0] = __float22bfloat162_rn(make_float2(p0, p1));
                pk.h2[1] = __float22bfloat162_rn(make_float2(p2, p3));
                *(uint2*)(pbase + pwc[n]) = pk.w;
            }
            bf16x8 pf0 = *(const bf16x8*)(pbase + prc[0]);
            bf16x8 pf1 = *(const bf16x8*)(pbase + prc[1]);
            #pragma unroll
            for (int dt = 0; dt < 4; ++dt) {
                f32x4 o = oacc[g][dt];
                o = __builtin_amdgcn_mfma_f32_16x16x32_bf16(vf[dt][0], pf0, o, 0, 0, 0);
                o = __builtin_amdgcn_mfma_f32_16x16x32_bf16(vf[dt][1], pf1, o, 0, 0, 0);
                oacc[g][dt] = o;
            }
        }
        #pragma unroll
        for (int n = 0; n < 4; ++n) {
            kf[n][0] = knx[n][0];
            kf[n][1] = knx[n][1];
        }
    }

    // partial l across quads, publish per-wave
    #pragma unroll
    for (int g = 0; g < 4; ++g) {
        rs[g] += __shfl_xor(rs[g], 16);
        rs[g] += __shfl_xor(rs[g], 32);
    }
    if (lane < 16) {
        #pragma unroll
        for (int g = 0; g < 4; ++g) lbc[wave][g * 16 + lane] = rs[g];
    }
    __syncthreads();

    const int rq = tid >> 2, seg = tid & 3;
    const float linv = 1.0f / (lbc[0][rq] + lbc[1][rq] + lbc[2][rq] + lbc[3][rq]);
    float* op = out + ((long)(b * S_LEN + q0 + rq)) * 1024 + h * 64;

    // merge partial O across waves in 4 d-quarters
    #pragma unroll
    for (int ph = 0; ph < 4; ++ph) {
        #pragma unroll
        for (int g = 0; g < 4; ++g)
            *(f32x4*)&Old[wave][(g * 16 + l15) * 20 + quad * 4] = oacc[g][ph];
        __syncthreads();
        f32x4 a = (f32x4){0.f, 0.f, 0.f, 0.f};
        #pragma unroll
        for (int w = 0; w < 4; ++w) a += *(const f32x4*)&Old[w][rq * 20 + seg * 4];
        *(float4*)(op + ph * 16 + seg * 4) =
            make_float4(a[0] * linv, a[1] * linv, a[2] * linv, a[3] * linv);
        __syncthreads();
    }
}

extern "C" void kernel_launch(void* const* d_in, const int* in_sizes, int n_in,
                              void* d_out, int out_size, void* d_ws, size_t ws_size,
                              hipStream_t stream) {
    const float* kin = (const float*)d_in[0];
    const float* qin = (const float*)d_in[1];
    const float* vin = (const float*)d_in[2];
    const float* Wk  = (const float*)d_in[3];
    const float* Wq  = (const float*)d_in[4];
    const float* Wv  = (const float*)d_in[5];
    float* out = (float*)d_out;

    u16* wsp = (u16*)d_ws;
    u16* Kh = wsp;
    u16* Qh = wsp + (long)HEAD_ELEMS;
    u16* Vt = wsp + 2 * (long)HEAD_ELEMS;

    dim3 kqg(256, 2, 2);
    proj_kq<<<kqg, 256, 0, stream>>>(kin, qin, Wk, Wq, Kh, Qh);
    dim3 vg(64, 16);
    proj_v<<<vg, 256, 0, stream>>>(vin, Wv, Vt);
    dim3 g(S_LEN / 64, NB * NH);
    attn_kernel<<<g, 256, 0, stream>>>(Qh, Kh, Vt, out);
}

// Round 6
// 304.148 us; speedup vs baseline: 1.2320x; 1.2320x over previous
//
#include <hip/hip_runtime.h>
#include <hip/hip_bf16.h>

typedef unsigned short u16;
typedef __bf16 bf16x8 __attribute__((ext_vector_type(8)));
typedef float f32x4 __attribute__((ext_vector_type(4)));

#define S_LEN 2048
#define NH 16
#define NB 2
#define HEAD_ELEMS (NB * NH * S_LEN * 64)

#if __has_builtin(__builtin_amdgcn_exp2f)
#define EXP2(x) __builtin_amdgcn_exp2f(x)
#else
#define EXP2(x) exp2f(x)
#endif

// 1/sqrt(64) * log2(e), folded into Wq. Scores come out in log2 units.
#define QSCALE 0.180336880f
#define SHIFT2 30.0f

__device__ __forceinline__ bf16x8 pack8(float4 a, float4 b, float sc) {
    union { bf16x8 v; __hip_bfloat162 h[4]; } r;
    r.h[0] = __float22bfloat162_rn(make_float2(a.x * sc, a.y * sc));
    r.h[1] = __float22bfloat162_rn(make_float2(a.z * sc, a.w * sc));
    r.h[2] = __float22bfloat162_rn(make_float2(b.x * sc, b.y * sc));
    r.h[3] = __float22bfloat162_rn(make_float2(b.z * sc, b.w * sc));
    return r.v;
}

// ---------------- K/Q projection, coalesced epilogue ----------------
// grid (stile 0..255, p 0..1, hhalf 0..1); 4 waves; wave = 16 rows x 2 heads.
__global__ __launch_bounds__(256) void proj_kq(
    const float* __restrict__ kin, const float* __restrict__ qin,
    const float* __restrict__ Wk, const float* __restrict__ Wq,
    u16* __restrict__ Kh, u16* __restrict__ Qh)
{
    __shared__ __align__(16) u16 Yld[8 * 16 * 72];

    const int tid = threadIdx.x;
    const int wave = tid >> 6;
    const int lane = tid & 63;
    const int quad = lane >> 4;
    const int l15 = lane & 15;
    const int stile = blockIdx.x;
    const int p = blockIdx.y;
    const int hh = blockIdx.z;
    const long row0 = (long)stile * 16;
    const int b = (int)(row0 >> 11);
    const int s0 = (int)(row0 & 2047);

    const float* X = p ? qin : kin;
    const float* W = p ? Wq : Wk;
    const float sc = p ? QSCALE : 1.0f;

    // issue x loads (HBM, longest latency) FIRST, then W (L2-resident)
    const float* xr0 = X + (row0 + l15) * 1024 + (hh * 8 + wave * 2) * 64 + quad * 8;
    const float* xr1 = xr0 + 64;
    float4 xa[4], xb[4];
    xa[0] = *(const float4*)(xr0);      xa[1] = *(const float4*)(xr0 + 4);
    xa[2] = *(const float4*)(xr0 + 32); xa[3] = *(const float4*)(xr0 + 36);
    xb[0] = *(const float4*)(xr1);      xb[1] = *(const float4*)(xr1 + 4);
    xb[2] = *(const float4*)(xr1 + 32); xb[3] = *(const float4*)(xr1 + 36);

    bf16x8 wf[4][2];
    #pragma unroll
    for (int nt = 0; nt < 4; ++nt) {
        const float* wr = W + (nt * 16 + l15) * 64 + quad * 8;
        wf[nt][0] = pack8(*(const float4*)(wr),      *(const float4*)(wr + 4),  sc);
        wf[nt][1] = pack8(*(const float4*)(wr + 32), *(const float4*)(wr + 36), sc);
    }

    #pragma unroll
    for (int hp = 0; hp < 2; ++hp) {
        const int hl = wave * 2 + hp;            // 0..7
        bf16x8 a0 = pack8(hp ? xb[0] : xa[0], hp ? xb[1] : xa[1], 1.0f);
        bf16x8 a1 = pack8(hp ? xb[2] : xa[2], hp ? xb[3] : xa[3], 1.0f);
        #pragma unroll
        for (int nt = 0; nt < 4; ++nt) {
            f32x4 c = (f32x4){0.f, 0.f, 0.f, 0.f};
            c = __builtin_amdgcn_mfma_f32_16x16x32_bf16(a0, wf[nt][0], c, 0, 0, 0);
            c = __builtin_amdgcn_mfma_f32_16x16x32_bf16(a1, wf[nt][1], c, 0, 0, 0);
            union { __hip_bfloat162 h2; u16 u[2]; } x01, x23;
            x01.h2 = __float22bfloat162_rn(make_float2(c[0], c[1]));
            x23.h2 = __float22bfloat162_rn(make_float2(c[2], c[3]));
            int base = (hl * 16 + quad * 4) * 72 + nt * 16 + l15;
            Yld[base]       = x01.u[0];
            Yld[base + 72]  = x01.u[1];
            Yld[base + 144] = x23.u[0];
            Yld[base + 216] = x23.u[1];
        }
    }
    __syncthreads();

    u16* dst = p ? Qh : Kh;
    #pragma unroll
    for (int it = 0; it < 4; ++it) {
        int idx = tid + it * 256;                // 0..1023
        int eg = idx & 7, s = (idx >> 3) & 15, hl = idx >> 7;
        int bh = b * NH + hh * 8 + hl;
        *(float4*)(dst + ((long)bh * S_LEN + s0 + s) * 64 + eg * 8) =
            *(const float4*)&Yld[(hl * 16 + s) * 72 + eg * 8];
    }
}

// ---------------- V projection (transposed out), coalesced epilogue ----------------
__global__ __launch_bounds__(256) void proj_v(
    const float* __restrict__ vin, const float* __restrict__ Wv, u16* __restrict__ Vt)
{
    __shared__ __align__(16) u16 Vtile[64 * 72];

    const int tid = threadIdx.x;
    const int wave = tid >> 6;
    const int lane = tid & 63;
    const int quad = lane >> 4;
    const int l15 = lane & 15;
    const long row0 = (long)blockIdx.x * 64;
    const int b = (int)(row0 >> 11);
    const int s0 = (int)(row0 & 2047);
    const int h = blockIdx.y;
    const int bh = b * NH + h;

    // x loads first (HBM), then W (L2)
    const float* xr = vin + (row0 + wave * 16 + l15) * 1024 + h * 64 + quad * 8;
    float4 x4[4];
    x4[0] = *(const float4*)(xr);      x4[1] = *(const float4*)(xr + 4);
    x4[2] = *(const float4*)(xr + 32); x4[3] = *(const float4*)(xr + 36);

    bf16x8 wf[4][2];
    #pragma unroll
    for (int dt = 0; dt < 4; ++dt) {
        const float* wr = Wv + (dt * 16 + l15) * 64 + quad * 8;
        wf[dt][0] = pack8(*(const float4*)(wr),      *(const float4*)(wr + 4),  1.0f);
        wf[dt][1] = pack8(*(const float4*)(wr + 32), *(const float4*)(wr + 36), 1.0f);
    }

    bf16x8 x0 = pack8(x4[0], x4[1], 1.0f);
    bf16x8 x1 = pack8(x4[2], x4[3], 1.0f);

    #pragma unroll
    for (int dt = 0; dt < 4; ++dt) {
        f32x4 c = (f32x4){0.f, 0.f, 0.f, 0.f};
        c = __builtin_amdgcn_mfma_f32_16x16x32_bf16(wf[dt][0], x0, c, 0, 0, 0);
        c = __builtin_amdgcn_mfma_f32_16x16x32_bf16(wf[dt][1], x1, c, 0, 0, 0);
        int base = (dt * 16 + quad * 4) * 72 + wave * 16 + l15;
        union { __hip_bfloat162 h2; u16 u[2]; } x01, x23;
        x01.h2 = __float22bfloat162_rn(make_float2(c[0], c[1]));
        x23.h2 = __float22bfloat162_rn(make_float2(c[2], c[3]));
        Vtile[base]       = x01.u[0];
        Vtile[base + 72]  = x01.u[1];
        Vtile[base + 144] = x23.u[0];
        Vtile[base + 216] = x23.u[1];
    }
    __syncthreads();

    u16* dst = Vt + (long)bh * 64 * S_LEN + s0;
    #pragma unroll
    for (int it = 0; it < 2; ++it) {
        int idx = tid + it * 256;                // 0..511
        int sg = idx & 7, e = idx >> 3;
        *(float4*)(dst + (long)e * S_LEN + sg * 8) = *(const float4*)&Vtile[e * 72 + sg * 8];
    }
}

// ---------------- attention: kv-split waves, permuted-K => zero-cost P transpose ----
// grid (qb=32, bh=32), 4 waves. Wave w owns kv tiles w, w+4, ...; partial O^T/l
// merged at the end (fixed-shift softmax is linear). K A-frag lane m loads K row
// kv = c*32 + (m>>2)*8 + nn*4 + (m&3), so QK output sacc[nn][r]@(quad,l15) IS the
// PV B-frag element P^T[c*32+quad*8+nn*4+r][q=l15]: exp+pack feeds MFMA directly.
__global__ __launch_bounds__(256, 3) void attn_kernel(
    const u16* __restrict__ Qh, const u16* __restrict__ Kh,
    const u16* __restrict__ Vt, float* __restrict__ out)
{
    __shared__ __align__(16) u16 Qld[64 * 72];      // Q tile, shared by all 4 waves
    __shared__ __align__(16) float Old[4][64 * 20];
    __shared__ float lbc[4][64];

    const int tid = threadIdx.x;
    const int wave = tid >> 6;
    const int lane = tid & 63;
    const int quad = lane >> 4;
    const int l15 = lane & 15;
    const int qb = blockIdx.x;
    const int bh = blockIdx.y;
    const int b = bh >> 4, h = bh & 15;
    const int q0 = qb * 64;
    const u16* kb = Kh + (long)bh * S_LEN * 64;
    const u16* vb = Vt + (long)bh * 64 * S_LEN;

    // stage Q tile [64 q][64 d] (row-major, pad 72)
    {
        const u16* qp = Qh + ((long)bh * S_LEN + q0) * 64;
        #pragma unroll
        for (int i = 0; i < 2; ++i) {
            int idx = tid + i * 256;
            int row = idx >> 3, gg = idx & 7;
            *(float4*)&Qld[row * 72 + gg * 8] = *(const float4*)(qp + row * 64 + gg * 8);
        }
    }
    __syncthreads();

    const int krow_off = ((l15 >> 2) * 8 + (l15 & 3)) * 64;   // permuted K row (elems)

    f32x4 oacc[4][4];
    #pragma unroll
    for (int g = 0; g < 4; ++g)
        #pragma unroll
        for (int dt = 0; dt < 4; ++dt) oacc[g][dt] = (f32x4){0.f, 0.f, 0.f, 0.f};
    float rs[4] = {0.f, 0.f, 0.f, 0.f};

    for (int kt = wave; kt < S_LEN / 64; kt += 4) {
        const u16* kt_p = kb + (long)kt * 4096;
        const u16* vt_p = vb + kt * 64;
        #pragma unroll
        for (int c = 0; c < 2; ++c) {
            bf16x8 kf[2][2], vf[4];
            #pragma unroll
            for (int nn = 0; nn < 2; ++nn) {
                const u16* kr = kt_p + c * 2048 + krow_off + nn * 256 + quad * 8;
                kf[nn][0] = *(const bf16x8*)(kr);
                kf[nn][1] = *(const bf16x8*)(kr + 32);
            }
            #pragma unroll
            for (int dt = 0; dt < 4; ++dt)
                vf[dt] = *(const bf16x8*)(vt_p + (long)(dt * 16 + l15) * S_LEN + c * 32 + quad * 8);

            #pragma unroll
            for (int g = 0; g < 4; ++g) {
                const u16* qrow = &Qld[(g * 16 + l15) * 72 + quad * 8];
                bf16x8 qb0 = *(const bf16x8*)(qrow);
                bf16x8 qb1 = *(const bf16x8*)(qrow + 32);
                f32x4 s0 = (f32x4){0.f, 0.f, 0.f, 0.f};
                f32x4 s1 = (f32x4){0.f, 0.f, 0.f, 0.f};
                s0 = __builtin_amdgcn_mfma_f32_16x16x32_bf16(kf[0][0], qb0, s0, 0, 0, 0);
                s0 = __builtin_amdgcn_mfma_f32_16x16x32_bf16(kf[0][1], qb1, s0, 0, 0, 0);
                s1 = __builtin_amdgcn_mfma_f32_16x16x32_bf16(kf[1][0], qb0, s1, 0, 0, 0);
                s1 = __builtin_amdgcn_mfma_f32_16x16x32_bf16(kf[1][1], qb1, s1, 0, 0, 0);

                float p00 = EXP2(s0[0] - SHIFT2), p01 = EXP2(s0[1] - SHIFT2);
                float p02 = EXP2(s0[2] - SHIFT2), p03 = EXP2(s0[3] - SHIFT2);
                float p10 = EXP2(s1[0] - SHIFT2), p11 = EXP2(s1[1] - SHIFT2);
                float p12 = EXP2(s1[2] - SHIFT2), p13 = EXP2(s1[3] - SHIFT2);
                rs[g] += ((p00 + p01) + (p02 + p03)) + ((p10 + p11) + (p12 + p13));

                union { bf16x8 v; __hip_bfloat162 h2[4]; } pf;
                pf.h2[0] = __float22bfloat162_rn(make_float2(p00, p01));
                pf.h2[1] = __float22bfloat162_rn(make_float2(p02, p03));
                pf.h2[2] = __float22bfloat162_rn(make_float2(p10, p11));
                pf.h2[3] = __float22bfloat162_rn(make_float2(p12, p13));

                #pragma unroll
                for (int dt = 0; dt < 4; ++dt)
                    oacc[g][dt] = __builtin_amdgcn_mfma_f32_16x16x32_bf16(vf[dt], pf.v, oacc[g][dt], 0, 0, 0);
            }
        }
    }

    // partial l across quads, publish per-wave
    #pragma unroll
    for (int g = 0; g < 4; ++g) {
        rs[g] += __shfl_xor(rs[g], 16);
        rs[g] += __shfl_xor(rs[g], 32);
    }
    if (lane < 16) {
        #pragma unroll
        for (int g = 0; g < 4; ++g) lbc[wave][g * 16 + lane] = rs[g];
    }
    __syncthreads();

    const int rq = tid >> 2, seg = tid & 3;
    const float linv = 1.0f / (lbc[0][rq] + lbc[1][rq] + lbc[2][rq] + lbc[3][rq]);
    float* op = out + ((long)(b * S_LEN + q0 + rq)) * 1024 + h * 64;

    // merge partial O across waves in 4 d-quarters
    #pragma unroll
    for (int ph = 0; ph < 4; ++ph) {
        #pragma unroll
        for (int g = 0; g < 4; ++g)
            *(f32x4*)&Old[wave][(g * 16 + l15) * 20 + quad * 4] = oacc[g][ph];
        __syncthreads();
        f32x4 a = (f32x4){0.f, 0.f, 0.f, 0.f};
        #pragma unroll
        for (int w = 0; w < 4; ++w) a += *(const f32x4*)&Old[w][rq * 20 + seg * 4];
        *(float4*)(op + ph * 16 + seg * 4) =
            make_float4(a[0] * linv, a[1] * linv, a[2] * linv, a[3] * linv);
        __syncthreads();
    }
}

extern "C" void kernel_launch(void* const* d_in, const int* in_sizes, int n_in,
                              void* d_out, int out_size, void* d_ws, size_t ws_size,
                              hipStream_t stream) {
    const float* kin = (const float*)d_in[0];
    const float* qin = (const float*)d_in[1];
    const float* vin = (const float*)d_in[2];
    const float* Wk  = (const float*)d_in[3];
    const float* Wq  = (const float*)d_in[4];
    const float* Wv  = (const float*)d_in[5];
    float* out = (float*)d_out;

    u16* wsp = (u16*)d_ws;
    u16* Kh = wsp;
    u16* Qh = wsp + (long)HEAD_ELEMS;
    u16* Vt = wsp + 2 * (long)HEAD_ELEMS;

    dim3 kqg(256, 2, 2);
    proj_kq<<<kqg, 256, 0, stream>>>(kin, qin, Wk, Wq, Kh, Qh);
    dim3 vg(64, 16);
    proj_v<<<vg, 256, 0, stream>>>(vin, Wv, Vt);
    dim3 g(S_LEN / 64, NB * NH);
    attn_kernel<<<g, 256, 0, stream>>>(Qh, Kh, Vt, out);
}

// Round 7
// 177.122 us; speedup vs baseline: 2.1156x; 1.7172x over previous
//
#include <hip/hip_runtime.h>
#include <hip/hip_bf16.h>

typedef unsigned short u16;
typedef __bf16 bf16x8 __attribute__((ext_vector_type(8)));
typedef float f32x4 __attribute__((ext_vector_type(4)));

#define S_LEN 2048
#define NH 16
#define NB 2
#define HEAD_ELEMS (NB * NH * S_LEN * 64)

#if __has_builtin(__builtin_amdgcn_exp2f)
#define EXP2(x) __builtin_amdgcn_exp2f(x)
#else
#define EXP2(x) exp2f(x)
#endif

// 1/sqrt(64) * log2(e), folded into Wq. Scores come out in log2 units.
#define QSCALE 0.180336880f
#define SHIFT2 30.0f

__device__ __forceinline__ bf16x8 pack8(float4 a, float4 b, float sc) {
    union { bf16x8 v; __hip_bfloat162 h[4]; } r;
    r.h[0] = __float22bfloat162_rn(make_float2(a.x * sc, a.y * sc));
    r.h[1] = __float22bfloat162_rn(make_float2(a.z * sc, a.w * sc));
    r.h[2] = __float22bfloat162_rn(make_float2(b.x * sc, b.y * sc));
    r.h[3] = __float22bfloat162_rn(make_float2(b.z * sc, b.w * sc));
    return r.v;
}

// ---------------- K/Q projection, coalesced epilogue ----------------
// grid (stile 0..255, p 0..1, hhalf 0..1); 4 waves; wave = 16 rows x 2 heads.
__global__ __launch_bounds__(256) void proj_kq(
    const float* __restrict__ kin, const float* __restrict__ qin,
    const float* __restrict__ Wk, const float* __restrict__ Wq,
    u16* __restrict__ Kh, u16* __restrict__ Qh)
{
    __shared__ __align__(16) u16 Yld[8 * 16 * 72];

    const int tid = threadIdx.x;
    const int wave = tid >> 6;
    const int lane = tid & 63;
    const int quad = lane >> 4;
    const int l15 = lane & 15;
    const int stile = blockIdx.x;
    const int p = blockIdx.y;
    const int hh = blockIdx.z;
    const long row0 = (long)stile * 16;
    const int b = (int)(row0 >> 11);
    const int s0 = (int)(row0 & 2047);

    const float* X = p ? qin : kin;
    const float* W = p ? Wq : Wk;
    const float sc = p ? QSCALE : 1.0f;

    // issue x loads (HBM, longest latency) FIRST, then W (L2-resident)
    const float* xr0 = X + (row0 + l15) * 1024 + (hh * 8 + wave * 2) * 64 + quad * 8;
    const float* xr1 = xr0 + 64;
    float4 xa[4], xb[4];
    xa[0] = *(const float4*)(xr0);      xa[1] = *(const float4*)(xr0 + 4);
    xa[2] = *(const float4*)(xr0 + 32); xa[3] = *(const float4*)(xr0 + 36);
    xb[0] = *(const float4*)(xr1);      xb[1] = *(const float4*)(xr1 + 4);
    xb[2] = *(const float4*)(xr1 + 32); xb[3] = *(const float4*)(xr1 + 36);

    bf16x8 wf[4][2];
    #pragma unroll
    for (int nt = 0; nt < 4; ++nt) {
        const float* wr = W + (nt * 16 + l15) * 64 + quad * 8;
        wf[nt][0] = pack8(*(const float4*)(wr),      *(const float4*)(wr + 4),  sc);
        wf[nt][1] = pack8(*(const float4*)(wr + 32), *(const float4*)(wr + 36), sc);
    }

    #pragma unroll
    for (int hp = 0; hp < 2; ++hp) {
        const int hl = wave * 2 + hp;            // 0..7
        bf16x8 a0 = pack8(hp ? xb[0] : xa[0], hp ? xb[1] : xa[1], 1.0f);
        bf16x8 a1 = pack8(hp ? xb[2] : xa[2], hp ? xb[3] : xa[3], 1.0f);
        #pragma unroll
        for (int nt = 0; nt < 4; ++nt) {
            f32x4 c = (f32x4){0.f, 0.f, 0.f, 0.f};
            c = __builtin_amdgcn_mfma_f32_16x16x32_bf16(a0, wf[nt][0], c, 0, 0, 0);
            c = __builtin_amdgcn_mfma_f32_16x16x32_bf16(a1, wf[nt][1], c, 0, 0, 0);
            union { __hip_bfloat162 h2; u16 u[2]; } x01, x23;
            x01.h2 = __float22bfloat162_rn(make_float2(c[0], c[1]));
            x23.h2 = __float22bfloat162_rn(make_float2(c[2], c[3]));
            int base = (hl * 16 + quad * 4) * 72 + nt * 16 + l15;
            Yld[base]       = x01.u[0];
            Yld[base + 72]  = x01.u[1];
            Yld[base + 144] = x23.u[0];
            Yld[base + 216] = x23.u[1];
        }
    }
    __syncthreads();

    u16* dst = p ? Qh : Kh;
    #pragma unroll
    for (int it = 0; it < 4; ++it) {
        int idx = tid + it * 256;                // 0..1023
        int eg = idx & 7, s = (idx >> 3) & 15, hl = idx >> 7;
        int bh = b * NH + hh * 8 + hl;
        *(float4*)(dst + ((long)bh * S_LEN + s0 + s) * 64 + eg * 8) =
            *(const float4*)&Yld[(hl * 16 + s) * 72 + eg * 8];
    }
}

// ---------------- V projection (transposed out), coalesced epilogue ----------------
__global__ __launch_bounds__(256) void proj_v(
    const float* __restrict__ vin, const float* __restrict__ Wv, u16* __restrict__ Vt)
{
    __shared__ __align__(16) u16 Vtile[64 * 72];

    const int tid = threadIdx.x;
    const int wave = tid >> 6;
    const int lane = tid & 63;
    const int quad = lane >> 4;
    const int l15 = lane & 15;
    const long row0 = (long)blockIdx.x * 64;
    const int b = (int)(row0 >> 11);
    const int s0 = (int)(row0 & 2047);
    const int h = blockIdx.y;
    const int bh = b * NH + h;

    // x loads first (HBM), then W (L2)
    const float* xr = vin + (row0 + wave * 16 + l15) * 1024 + h * 64 + quad * 8;
    float4 x4[4];
    x4[0] = *(const float4*)(xr);      x4[1] = *(const float4*)(xr + 4);
    x4[2] = *(const float4*)(xr + 32); x4[3] = *(const float4*)(xr + 36);

    bf16x8 wf[4][2];
    #pragma unroll
    for (int dt = 0; dt < 4; ++dt) {
        const float* wr = Wv + (dt * 16 + l15) * 64 + quad * 8;
        wf[dt][0] = pack8(*(const float4*)(wr),      *(const float4*)(wr + 4),  1.0f);
        wf[dt][1] = pack8(*(const float4*)(wr + 32), *(const float4*)(wr + 36), 1.0f);
    }

    bf16x8 x0 = pack8(x4[0], x4[1], 1.0f);
    bf16x8 x1 = pack8(x4[2], x4[3], 1.0f);

    #pragma unroll
    for (int dt = 0; dt < 4; ++dt) {
        f32x4 c = (f32x4){0.f, 0.f, 0.f, 0.f};
        c = __builtin_amdgcn_mfma_f32_16x16x32_bf16(wf[dt][0], x0, c, 0, 0, 0);
        c = __builtin_amdgcn_mfma_f32_16x16x32_bf16(wf[dt][1], x1, c, 0, 0, 0);
        int base = (dt * 16 + quad * 4) * 72 + wave * 16 + l15;
        union { __hip_bfloat162 h2; u16 u[2]; } x01, x23;
        x01.h2 = __float22bfloat162_rn(make_float2(c[0], c[1]));
        x23.h2 = __float22bfloat162_rn(make_float2(c[2], c[3]));
        Vtile[base]       = x01.u[0];
        Vtile[base + 72]  = x01.u[1];
        Vtile[base + 144] = x23.u[0];
        Vtile[base + 216] = x23.u[1];
    }
    __syncthreads();

    u16* dst = Vt + (long)bh * 64 * S_LEN + s0;
    #pragma unroll
    for (int it = 0; it < 2; ++it) {
        int idx = tid + it * 256;                // 0..511
        int sg = idx & 7, e = idx >> 3;
        *(float4*)(dst + (long)e * S_LEN + sg * 8) = *(const float4*)&Vtile[e * 72 + sg * 8];
    }
}

// ---------------- attention: kv-split waves, permuted-K => zero-cost P transpose ----
// grid (qb=32, bh=32), 4 waves. Wave w owns kv tiles w, w+4, ...; partial O^T/l
// merged at the end (fixed-shift softmax is linear). K A-frag lane m loads K row
// kv = c*32 + (m>>2)*8 + nn*4 + (m&3), so QK output sacc[nn][r]@(quad,l15) IS the
// PV B-frag element P^T[c*32+quad*8+nn*4+r][q=l15]: exp+pack feeds MFMA directly.
// launch_bounds: (256,2) — (256,3) capped VGPR at 84 and spilled ~700MB (R5/R6).
__global__ __launch_bounds__(256, 2) void attn_kernel(
    const u16* __restrict__ Qh, const u16* __restrict__ Kh,
    const u16* __restrict__ Vt, float* __restrict__ out)
{
    __shared__ __align__(16) u16 Qld[64 * 72];      // Q tile, shared by all 4 waves
    __shared__ __align__(16) float Old[4][64 * 20];
    __shared__ float lbc[4][64];

    const int tid = threadIdx.x;
    const int wave = tid >> 6;
    const int lane = tid & 63;
    const int quad = lane >> 4;
    const int l15 = lane & 15;
    const int qb = blockIdx.x;
    const int bh = blockIdx.y;
    const int b = bh >> 4, h = bh & 15;
    const int q0 = qb * 64;
    const u16* kb = Kh + (long)bh * S_LEN * 64;
    const u16* vb = Vt + (long)bh * 64 * S_LEN;

    // stage Q tile [64 q][64 d] (row-major, pad 72)
    {
        const u16* qp = Qh + ((long)bh * S_LEN + q0) * 64;
        #pragma unroll
        for (int i = 0; i < 2; ++i) {
            int idx = tid + i * 256;
            int row = idx >> 3, gg = idx & 7;
            *(float4*)&Qld[row * 72 + gg * 8] = *(const float4*)(qp + row * 64 + gg * 8);
        }
    }
    __syncthreads();

    const int krow_off = ((l15 >> 2) * 8 + (l15 & 3)) * 64;   // permuted K row (elems)

    f32x4 oacc[4][4];
    #pragma unroll
    for (int g = 0; g < 4; ++g)
        #pragma unroll
        for (int dt = 0; dt < 4; ++dt) oacc[g][dt] = (f32x4){0.f, 0.f, 0.f, 0.f};
    float rs[4] = {0.f, 0.f, 0.f, 0.f};

    for (int kt = wave; kt < S_LEN / 64; kt += 4) {
        const u16* kt_p = kb + (long)kt * 4096;
        const u16* vt_p = vb + kt * 64;
        #pragma unroll
        for (int c = 0; c < 2; ++c) {
            bf16x8 kf[2][2], vf[4];
            #pragma unroll
            for (int nn = 0; nn < 2; ++nn) {
                const u16* kr = kt_p + c * 2048 + krow_off + nn * 256 + quad * 8;
                kf[nn][0] = *(const bf16x8*)(kr);
                kf[nn][1] = *(const bf16x8*)(kr + 32);
            }
            #pragma unroll
            for (int dt = 0; dt < 4; ++dt)
                vf[dt] = *(const bf16x8*)(vt_p + (long)(dt * 16 + l15) * S_LEN + c * 32 + quad * 8);

            #pragma unroll
            for (int g = 0; g < 4; ++g) {
                const u16* qrow = &Qld[(g * 16 + l15) * 72 + quad * 8];
                bf16x8 qb0 = *(const bf16x8*)(qrow);
                bf16x8 qb1 = *(const bf16x8*)(qrow + 32);
                f32x4 s0 = (f32x4){0.f, 0.f, 0.f, 0.f};
                f32x4 s1 = (f32x4){0.f, 0.f, 0.f, 0.f};
                s0 = __builtin_amdgcn_mfma_f32_16x16x32_bf16(kf[0][0], qb0, s0, 0, 0, 0);
                s0 = __builtin_amdgcn_mfma_f32_16x16x32_bf16(kf[0][1], qb1, s0, 0, 0, 0);
                s1 = __builtin_amdgcn_mfma_f32_16x16x32_bf16(kf[1][0], qb0, s1, 0, 0, 0);
                s1 = __builtin_amdgcn_mfma_f32_16x16x32_bf16(kf[1][1], qb1, s1, 0, 0, 0);

                float p00 = EXP2(s0[0] - SHIFT2), p01 = EXP2(s0[1] - SHIFT2);
                float p02 = EXP2(s0[2] - SHIFT2), p03 = EXP2(s0[3] - SHIFT2);
                float p10 = EXP2(s1[0] - SHIFT2), p11 = EXP2(s1[1] - SHIFT2);
                float p12 = EXP2(s1[2] - SHIFT2), p13 = EXP2(s1[3] - SHIFT2);
                rs[g] += ((p00 + p01) + (p02 + p03)) + ((p10 + p11) + (p12 + p13));

                union { bf16x8 v; __hip_bfloat162 h2[4]; } pf;
                pf.h2[0] = __float22bfloat162_rn(make_float2(p00, p01));
                pf.h2[1] = __float22bfloat162_rn(make_float2(p02, p03));
                pf.h2[2] = __float22bfloat162_rn(make_float2(p10, p11));
                pf.h2[3] = __float22bfloat162_rn(make_float2(p12, p13));

                #pragma unroll
                for (int dt = 0; dt < 4; ++dt)
                    oacc[g][dt] = __builtin_amdgcn_mfma_f32_16x16x32_bf16(vf[dt], pf.v, oacc[g][dt], 0, 0, 0);
            }
        }
    }

    // partial l across quads, publish per-wave
    #pragma unroll
    for (int g = 0; g < 4; ++g) {
        rs[g] += __shfl_xor(rs[g], 16);
        rs[g] += __shfl_xor(rs[g], 32);
    }
    if (lane < 16) {
        #pragma unroll
        for (int g = 0; g < 4; ++g) lbc[wave][g * 16 + lane] = rs[g];
    }
    __syncthreads();

    const int rq = tid >> 2, seg = tid & 3;
    const float linv = 1.0f / (lbc[0][rq] + lbc[1][rq] + lbc[2][rq] + lbc[3][rq]);
    float* op = out + ((long)(b * S_LEN + q0 + rq)) * 1024 + h * 64;

    // merge partial O across waves in 4 d-quarters
    #pragma unroll
    for (int ph = 0; ph < 4; ++ph) {
        #pragma unroll
        for (int g = 0; g < 4; ++g)
            *(f32x4*)&Old[wave][(g * 16 + l15) * 20 + quad * 4] = oacc[g][ph];
        __syncthreads();
        f32x4 a = (f32x4){0.f, 0.f, 0.f, 0.f};
        #pragma unroll
        for (int w = 0; w < 4; ++w) a += *(const f32x4*)&Old[w][rq * 20 + seg * 4];
        *(float4*)(op + ph * 16 + seg * 4) =
            make_float4(a[0] * linv, a[1] * linv, a[2] * linv, a[3] * linv);
        __syncthreads();
    }
}

extern "C" void kernel_launch(void* const* d_in, const int* in_sizes, int n_in,
                              void* d_out, int out_size, void* d_ws, size_t ws_size,
                              hipStream_t stream) {
    const float* kin = (const float*)d_in[0];
    const float* qin = (const float*)d_in[1];
    const float* vin = (const float*)d_in[2];
    const float* Wk  = (const float*)d_in[3];
    const float* Wq  = (const float*)d_in[4];
    const float* Wv  = (const float*)d_in[5];
    float* out = (float*)d_out;

    u16* wsp = (u16*)d_ws;
    u16* Kh = wsp;
    u16* Qh = wsp + (long)HEAD_ELEMS;
    u16* Vt = wsp + 2 * (long)HEAD_ELEMS;

    dim3 kqg(256, 2, 2);
    proj_kq<<<kqg, 256, 0, stream>>>(kin, qin, Wk, Wq, Kh, Qh);
    dim3 vg(64, 16);
    proj_v<<<vg, 256, 0, stream>>>(vin, Wv, Vt);
    dim3 g(S_LEN / 64, NB * NH);
    attn_kernel<<<g, 256, 0, stream>>>(Qh, Kh, Vt, out);
}